// Round 4
// baseline (308.154 us; speedup 1.0000x reference)
//
#include <hip/hip_runtime.h>
#include <math.h>

// RetNetRelPosDeform2D: B=8,H=8,N1=N2=32,slen=1024,D=64
// Outputs (fp32, flat-concatenated):
//   sin_q [8,8,1024,64]  @ 0
//   cos_q [8,8,1024,64]  @ 4194304
//   sin_k [1024,64]      @ 8388608
//   cos_k [1024,64]      @ 8454144
//   mask  [8,8,1024,1024]@ 8519680
#define OFF_COSQ  4194304
#define OFF_SINK  8388608
#define OFF_COSK  8454144
#define OFF_MASK  8519680
#define NROWS     65536   // B*H*slen

typedef float floatx4 __attribute__((ext_vector_type(4)));

// ---------------- Kernel A: per-row factor tables + rotary outputs ----------------
// One wave per query row. Computes the two 32-element exp factors ONCE per row
// (64 exps/row vs 576 in the fused version), folds invnorm into e1, stores the
// 64-float table to ws. Also emits sin_q/cos_q (and sin_k/cos_k for bh==0).
__global__ __launch_bounds__(256) void retnet_prep_kernel(
    const float* __restrict__ offsets,   // [B,H,32,32,2]
    const float* __restrict__ angle,     // [64]
    const float* __restrict__ decay,     // [8]
    float* __restrict__ out,
    float* __restrict__ ws)              // [NROWS][64]: e1*invnorm | e2
{
    const int wave = blockIdx.x * 4 + (threadIdx.x >> 6);
    const int lane = threadIdx.x & 63;

    const int bh = wave >> 10;      // b*8+h
    const int s  = wave & 1023;     // i*32+j
    const int h  = bh & 7;
    const int i  = s >> 5;
    const int j  = s & 31;

    const float off0 = offsets[(wave << 1) + 0];
    const float off1 = offsets[(wave << 1) + 1];
    const float i1q  = (float)i + off0;
    const float i2q  = (float)j + off1;
    const float dec  = decay[h];
    const float ang  = angle[lane];

    // sin_q / cos_q
    {
        float sq, cq;
        __sincosf((i1q + i2q) * ang, &sq, &cq);
        __builtin_nontemporal_store(sq, &out[(size_t)wave * 64 + lane]);
        __builtin_nontemporal_store(cq, &out[OFF_COSQ + (size_t)wave * 64 + lane]);
    }

    // sin_k / cos_k (first 1024 rows only)
    if (bh == 0) {
        float sk, ck;
        __sincosf((float)(i + j) * ang, &sk, &ck);
        __builtin_nontemporal_store(sk, &out[OFF_SINK + (size_t)s * 64 + lane]);
        __builtin_nontemporal_store(ck, &out[OFF_COSK + (size_t)s * 64 + lane]);
    }

    // factor table: lanes 0..31 -> e1[lane], lanes 32..63 -> e2[lane-32]
    float v;
    if (lane < 32) v = __expf(dec * fabsf(i1q - (float)lane));
    else           v = __expf(dec * fabsf(i2q - (float)(lane - 32)));

    // butterfly sum within each 32-lane half (xor masks <=16 stay in-half)
    float sum = v;
    #pragma unroll
    for (int m = 16; m >= 1; m >>= 1) sum += __shfl_xor(sum, m, 64);
    const float sum1 = __shfl(sum, 0, 64);
    const float sum2 = __shfl(sum, 32, 64);
    const float invnorm = rsqrtf(sum1 * sum2);

    ws[(size_t)wave * 64 + lane] = (lane < 32) ? v * invnorm : v;
}

// ---------------- Kernel B: pure mask streamer ----------------
// One wave per row: 1 float4 + 4 dword loads per lane (L2-warm 16 MB table),
// 16 muls, 4 nontemporal float4 stores. Store-bound by construction.
__global__ __launch_bounds__(256) void retnet_mask_kernel(
    const float* __restrict__ ws,
    float* __restrict__ out)
{
    const int wave = blockIdx.x * 4 + (threadIdx.x >> 6);
    const int lane = threadIdx.x & 63;

    const float* row = ws + (size_t)wave * 64;

    // mask float4 index f = k*64+lane -> ii = k*8 + (lane>>3), jj = (lane&7)*4 + c
    const int jj0 = (lane & 7) * 4;
    const floatx4 e2q = *(const floatx4*)(row + 32 + jj0);

    const int ii0 = lane >> 3;
    float e1a[4];
    #pragma unroll
    for (int k = 0; k < 4; ++k) e1a[k] = row[k * 8 + ii0];   // e1*invnorm

    floatx4* mrow = (floatx4*)(out + OFF_MASK + (size_t)wave * 1024);
    #pragma unroll
    for (int k = 0; k < 4; ++k) {
        floatx4 r = e2q * e1a[k];
        __builtin_nontemporal_store(r, &mrow[k * 64 + lane]);
    }
}

extern "C" void kernel_launch(void* const* d_in, const int* in_sizes, int n_in,
                              void* d_out, int out_size, void* d_ws, size_t ws_size,
                              hipStream_t stream) {
    // inputs: [0]=slen (int, unused), [1]=offsets fp32 [8,8,32,32,2],
    //         [2]=angle fp32 [64], [3]=decay fp32 [8]
    const float* offsets = (const float*)d_in[1];
    const float* angle   = (const float*)d_in[2];
    const float* decay   = (const float*)d_in[3];
    float* out = (float*)d_out;
    float* ws  = (float*)d_ws;   // needs 16.8 MB; ws_size ~3x out size

    const int blocks = NROWS / 4;  // 4 waves (rows) per 256-thread block
    retnet_prep_kernel<<<blocks, 256, 0, stream>>>(offsets, angle, decay, out, ws);
    retnet_mask_kernel<<<blocks, 256, 0, stream>>>(ws, out);
}

// Round 5
// 302.221 us; speedup vs baseline: 1.0196x; 1.0196x over previous
//
#include <hip/hip_runtime.h>
#include <math.h>

// RetNetRelPosDeform2D: B=8,H=8,N1=N2=32,slen=1024,D=64
// Outputs (fp32, flat-concatenated):
//   sin_q [8,8,1024,64]  @ 0
//   cos_q [8,8,1024,64]  @ 4194304
//   sin_k [1024,64]      @ 8388608
//   cos_k [1024,64]      @ 8454144
//   mask  [8,8,1024,1024]@ 8519680
#define OFF_COSQ  4194304
#define OFF_SINK  8388608
#define OFF_COSK  8454144
#define OFF_MASK  8519680
#define NROWS     65536   // B*H*slen

typedef float floatx4 __attribute__((ext_vector_type(4)));

// One wave per query row. The two 32-element exp factors are computed ONCE
// (one __expf per lane: lanes 0..31 -> e1[l], lanes 32..63 -> e2[l-32]);
// the mask tile factors are then gathered cross-lane via __shfl (ds_bpermute,
// idle LDS pipe) instead of recomputing 8 more __expf per lane (trans pipe).
__global__ __launch_bounds__(256) void retnet_fused_kernel(
    const float* __restrict__ offsets,   // [B,H,32,32,2]
    const float* __restrict__ angle,     // [64]
    const float* __restrict__ decay,     // [8]
    float* __restrict__ out)
{
    const int wave = blockIdx.x * 4 + (threadIdx.x >> 6); // one wave per query row
    const int lane = threadIdx.x & 63;

    const int bh = wave >> 10;      // b*8+h
    const int s  = wave & 1023;     // i*32+j
    const int h  = bh & 7;
    const int i  = s >> 5;
    const int j  = s & 31;

    const float off0 = offsets[(wave << 1) + 0];
    const float off1 = offsets[(wave << 1) + 1];
    const float i1q  = (float)i + off0;     // deformed row index
    const float i2q  = (float)j + off1;     // deformed col index
    const float dec  = decay[h];            // negative
    const float ang  = angle[lane];

    // ---- sin_q / cos_q (lane l handles dim d=l) ----
    {
        float sq, cq;
        __sincosf((i1q + i2q) * ang, &sq, &cq);
        __builtin_nontemporal_store(sq, &out[(size_t)wave * 64 + lane]);
        __builtin_nontemporal_store(cq, &out[OFF_COSQ + (size_t)wave * 64 + lane]);
    }

    // ---- sin_k / cos_k: only the first 1024 rows (bh==0) emit them ----
    if (bh == 0) {
        float sk, ck;
        __sincosf((float)(i + j) * ang, &sk, &ck);
        __builtin_nontemporal_store(sk, &out[OFF_SINK + (size_t)s * 64 + lane]);
        __builtin_nontemporal_store(ck, &out[OFF_COSK + (size_t)s * 64 + lane]);
    }

    // ---- mask row: exp(dec*(|i1q-ii|+|i2q-jj|)) / sqrt(sum1*sum2) ----
    // Single exp per lane: lanes 0..31 hold e1[lane], lanes 32..63 hold e2[lane-32].
    const int   l5   = lane & 31;
    const float base = (lane < 32) ? i1q : i2q;
    const float v    = __expf(dec * fabsf(base - (float)l5));

    // Butterfly reduce within each 32-lane half (xor masks <=16 stay in-half)
    float sum = v;
    #pragma unroll
    for (int m = 16; m >= 1; m >>= 1) sum += __shfl_xor(sum, m, 64);
    const float sum1 = __shfl(sum, 0, 64);    // sum over e1
    const float sum2 = __shfl(sum, 32, 64);   // sum over e2
    const float invnorm = rsqrtf(sum1 * sum2);

    // Fold invnorm into the e1 half so the per-element product is just e1s*e2.
    const float vs = (lane < 32) ? v * invnorm : v;

    // Gather the factors this lane needs via cross-lane shuffles (no recompute):
    // float4 index f = k*64+lane -> ii = k*8 + (lane>>3), jj = (lane&7)*4 + c
    const int jj0 = (lane & 7) * 4;
    floatx4 e2q;
    e2q.x = __shfl(vs, 32 + jj0 + 0, 64);
    e2q.y = __shfl(vs, 32 + jj0 + 1, 64);
    e2q.z = __shfl(vs, 32 + jj0 + 2, 64);
    e2q.w = __shfl(vs, 32 + jj0 + 3, 64);

    const int ii0 = lane >> 3;
    float e1a[4];
    #pragma unroll
    for (int k = 0; k < 4; ++k) e1a[k] = __shfl(vs, k * 8 + ii0, 64);  // e1*invnorm

    floatx4* mrow = (floatx4*)(out + OFF_MASK + (size_t)wave * 1024);
    #pragma unroll
    for (int k = 0; k < 4; ++k) {
        floatx4 r = e2q * e1a[k];
        __builtin_nontemporal_store(r, &mrow[k * 64 + lane]);
    }
}

extern "C" void kernel_launch(void* const* d_in, const int* in_sizes, int n_in,
                              void* d_out, int out_size, void* d_ws, size_t ws_size,
                              hipStream_t stream) {
    // inputs: [0]=slen (int, unused), [1]=offsets fp32 [8,8,32,32,2],
    //         [2]=angle fp32 [64], [3]=decay fp32 [8]
    const float* offsets = (const float*)d_in[1];
    const float* angle   = (const float*)d_in[2];
    const float* decay   = (const float*)d_in[3];
    float* out = (float*)d_out;

    const int blocks = NROWS / 4;  // 4 waves (rows) per 256-thread block
    retnet_fused_kernel<<<blocks, 256, 0, stream>>>(offsets, angle, decay, out);
}